// Round 15
// baseline (297.102 us; speedup 1.0000x reference)
//
#include <hip/hip_runtime.h>
#include <hip/hip_bf16.h>
#include <math.h>

typedef __attribute__((ext_vector_type(8))) short bf16x8;
typedef __attribute__((ext_vector_type(16))) float f32x16;

#define B_ 32
#define C_ 256
#define K_ 2048
#define HW_ 784
#define NPIX 25088
#define FEAT_BSTRIDE 230400
#define FEAT_CSTRIDE 900
#define INV_DELTA 15.0f
#define LOG2E 1.4426950408889634f
#define QSCALE 409.6f
#define QDEC (LOG2E / QSCALE)

#define BM 128
#define BN 128
#define NSLAB 16

__device__ __forceinline__ ushort f2bf(float x) {
    __hip_bfloat16 h = __float2bfloat16(x);
    return *reinterpret_cast<ushort*>(&h);
}
__device__ __forceinline__ float bf2f(ushort u) {
    __hip_bfloat16 h;
    *reinterpret_cast<ushort*>(&h) = u;
    return __bfloat162float(h);
}

// ---------------- e2[k] = sum_c emb[k][c]^2 (fp32 exact) ----------------
__global__ void e2_kernel(const float* __restrict__ emb, float* __restrict__ e2) {
    int t = threadIdx.x;
    int wid = t >> 6, lane = t & 63;
    int k = blockIdx.x * 4 + wid;
    const float* er = emb + (size_t)k * C_;
    float v0 = er[lane], v1 = er[lane + 64], v2 = er[lane + 128], v3 = er[lane + 192];
    float s = v0 * v0 + v1 * v1 + v2 * v2 + v3 * v3;
#pragma unroll
    for (int off = 32; off > 0; off >>= 1) s += __shfl_xor(s, off);
    if (lane == 0) e2[k] = s;
}

// ---------------- split embedding into bf16 hi/lo ----------------
__global__ void prep_e_kernel(const float* __restrict__ emb,
                              ushort* __restrict__ ehi, ushort* __restrict__ elo) {
    int i = blockIdx.x * 256 + threadIdx.x;
    float v = emb[i];
    ushort h = f2bf(v);
    float r = v - bf2f(h);
    ehi[i] = h;
    elo[i] = f2bf(r);
}

// ---------------- crop + transpose + split features into bf16 hi/lo [px][c] ----------------
__global__ __launch_bounds__(256) void prep_f_kernel(const float* __restrict__ feat,
                                                     ushort* __restrict__ fhi,
                                                     ushort* __restrict__ flo) {
    __shared__ float F[256 * 65];
    int t = threadIdx.x;
    int px0 = blockIdx.x * 64;
    {
        int lane = t & 63, cq = t >> 6;
        int px = px0 + lane;
        int b = px / HW_, hw = px % HW_;
        int h = hw / 28, w = hw % 28;
        const float* base = feat + (size_t)b * FEAT_BSTRIDE + (size_t)(h + 1) * 30 + (w + 1);
#pragma unroll
        for (int cc = 0; cc < 64; ++cc) {
            int c = cq * 64 + cc;
            F[c * 65 + lane] = base[(size_t)c * FEAT_CSTRIDE];
        }
    }
    __syncthreads();
    {
        int px_l = t >> 2, cseg = t & 3;
        size_t ob = (size_t)(px0 + px_l) * C_ + cseg * 64;
        uint uh[32], ul[32];
#pragma unroll
        for (int j = 0; j < 32; ++j) {
            float v0 = F[(cseg * 64 + 2 * j) * 65 + px_l];
            float v1 = F[(cseg * 64 + 2 * j + 1) * 65 + px_l];
            ushort h0 = f2bf(v0), h1 = f2bf(v1);
            float r0 = v0 - bf2f(h0), r1 = v1 - bf2f(h1);
            uh[j] = (uint)h0 | ((uint)h1 << 16);
            ul[j] = (uint)f2bf(r0) | ((uint)f2bf(r1) << 16);
        }
#pragma unroll
        for (int j = 0; j < 8; ++j) {
            *reinterpret_cast<uint4*>(&fhi[ob + j * 8]) = *reinterpret_cast<uint4*>(&uh[j * 4]);
            *reinterpret_cast<uint4*>(&flo[ob + j * 8]) = *reinterpret_cast<uint4*>(&ul[j * 4]);
        }
    }
}

// ---------------- MFMA GEMM: barrier-free, L2->VGPR, fenced 2-deep pipeline ----------------
// No LDS, no barriers, no waitcnt(0) anywhere in the K-loop. Each step issues the next
// step's 8 fragment loads, then a sched_barrier(0) fence (rule 18/19: hipcc otherwise
// sinks the loads to their uses, collapsing the pipeline -> R11's VGPR=84 failure),
// then the current step's 12 MFMAs. Compiler auto-emits counted vmcnt(8) before each
// MFMA cluster; 8 waves/CU x 16KB in flight provide the latency-hiding concurrency.
// SWAPPED operands (R14): D[k][px] -> lane-local k for the softmax epilogue.
__global__ __launch_bounds__(256, 2) void gemm_kernel(
    const ushort* __restrict__ fhi, const ushort* __restrict__ flo,
    const ushort* __restrict__ ehi, const ushort* __restrict__ elo,
    const float* __restrict__ mdm, const float* __restrict__ e2g,
    ushort* __restrict__ zq, float* __restrict__ m_part, float* __restrict__ l_part)
{
    __shared__ float redA[2][132];
    __shared__ float redM[132];

    int t = threadIdx.x;
    int lane = t & 63, wid = t >> 6;
    int wrow = wid >> 1, wcol = wid & 1;
    int g = lane >> 5, ci = lane & 31;

    int bid = blockIdx.x;                    // 0..3135
    int swz = (bid & 7) * 392 + (bid >> 3);  // bijective XCD chunks
    int tile = swz >> 4, slab = swz & 15;
    int px0 = tile * BM;
    int k0 = slab * BN;

    // per-lane fragment base pointers; step s adds s*16 (ushorts)
    const ushort* pfh[2];
    const ushort* pfl[2];
    const ushort* peh[2];
    const ushort* pel[2];
#pragma unroll
    for (int mi = 0; mi < 2; ++mi) {
        size_t r = (size_t)(px0 + wrow * 64 + mi * 32 + ci) * C_ + g * 8;
        pfh[mi] = fhi + r;
        pfl[mi] = flo + r;
    }
#pragma unroll
    for (int ni = 0; ni < 2; ++ni) {
        size_t r = (size_t)(k0 + wcol * 64 + ni * 32 + ci) * C_ + g * 8;
        peh[ni] = ehi + r;
        pel[ni] = elo + r;
    }

    f32x16 acc[2][2];   // [mi: px-tile][ni: k-tile]
#pragma unroll
    for (int mi = 0; mi < 2; ++mi)
#pragma unroll
        for (int ni = 0; ni < 2; ++ni)
            acc[mi][ni] = (f32x16)(0.0f);

    // 2-slot fragment pipeline, statically indexed (full unroll)
    bf16x8 fhS[2][2], flS[2][2], ehS[2][2], elS[2][2];   // [slot][mi/ni]
    auto ldf = [&](int slot, int s) {
        int off = s * 16;
#pragma unroll
        for (int mi = 0; mi < 2; ++mi) {
            fhS[slot][mi] = *reinterpret_cast<const bf16x8*>(pfh[mi] + off);
            flS[slot][mi] = *reinterpret_cast<const bf16x8*>(pfl[mi] + off);
        }
#pragma unroll
        for (int ni = 0; ni < 2; ++ni) {
            ehS[slot][ni] = *reinterpret_cast<const bf16x8*>(peh[ni] + off);
            elS[slot][ni] = *reinterpret_cast<const bf16x8*>(pel[ni] + off);
        }
    };

    ldf(0, 0);
    __builtin_amdgcn_sched_barrier(0);
#pragma unroll
    for (int s = 0; s < 16; ++s) {
        if (s + 1 < 16) ldf((s + 1) & 1, s + 1);   // prefetch next step's 8 fragments
        __builtin_amdgcn_sched_barrier(0);         // fence: loads may NOT sink below MFMAs
        int cs = s & 1;
#pragma unroll
        for (int mi = 0; mi < 2; ++mi)
#pragma unroll
            for (int ni = 0; ni < 2; ++ni) {
                acc[mi][ni] = __builtin_amdgcn_mfma_f32_32x32x16_bf16(ehS[cs][ni], fhS[cs][mi], acc[mi][ni], 0, 0, 0);
                acc[mi][ni] = __builtin_amdgcn_mfma_f32_32x32x16_bf16(elS[cs][ni], fhS[cs][mi], acc[mi][ni], 0, 0, 0);
                acc[mi][ni] = __builtin_amdgcn_mfma_f32_32x32x16_bf16(ehS[cs][ni], flS[cs][mi], acc[mi][ni], 0, 0, 0);
            }
        __builtin_amdgcn_sched_barrier(0);         // keep this step's MFMAs above next loads
    }

    // ---------------- epilogue (lane-local k, R14-verified) ----------------
    const float alpha = INV_DELTA / mdm[0];
    {
        const float* e2b = e2g + k0 + wcol * 64 + 4 * g;
#pragma unroll
        for (int ni = 0; ni < 2; ++ni)
#pragma unroll
            for (int q = 0; q < 4; ++q) {
                float4 ev = *reinterpret_cast<const float4*>(e2b + ni * 32 + 8 * q);
#pragma unroll
                for (int mi = 0; mi < 2; ++mi) {
                    acc[mi][ni][4 * q + 0] = alpha * (2.f * acc[mi][ni][4 * q + 0] - ev.x);
                    acc[mi][ni][4 * q + 1] = alpha * (2.f * acc[mi][ni][4 * q + 1] - ev.y);
                    acc[mi][ni][4 * q + 2] = alpha * (2.f * acc[mi][ni][4 * q + 2] - ev.z);
                    acc[mi][ni][4 * q + 3] = alpha * (2.f * acc[mi][ni][4 * q + 3] - ev.w);
                }
            }
    }

    float mt[2];
#pragma unroll
    for (int mi = 0; mi < 2; ++mi) {
        float m = acc[mi][0][0];
#pragma unroll
        for (int ni = 0; ni < 2; ++ni)
#pragma unroll
            for (int r = 0; r < 16; ++r) m = fmaxf(m, acc[mi][ni][r]);
        m = fmaxf(m, __shfl_xor(m, 32));
        mt[mi] = m;
        if (lane < 32) redA[wcol][wrow * 64 + mi * 32 + ci] = m;
    }
    __syncthreads();
    if (t < 128) redM[t] = fmaxf(redA[0][t], redA[1][t]);
    __syncthreads();
    float ms[2];
#pragma unroll
    for (int mi = 0; mi < 2; ++mi) ms[mi] = redM[wrow * 64 + mi * 32 + ci];

#pragma unroll
    for (int mi = 0; mi < 2; ++mi) {
        float l = 0.f;
#pragma unroll
        for (int ni = 0; ni < 2; ++ni)
#pragma unroll
            for (int r = 0; r < 16; ++r) l += exp2f((acc[mi][ni][r] - ms[mi]) * LOG2E);
        l += __shfl_xor(l, 32);
        if (lane < 32) redA[wcol][wrow * 64 + mi * 32 + ci] = l;
    }
    __syncthreads();
    if (t < 128) {
        m_part[(size_t)slab * NPIX + px0 + t] = redM[t];
        l_part[(size_t)slab * NPIX + px0 + t] = redA[0][t] + redA[1][t];
    }

    // quantized store: lane-local k runs; wave writes 64B px runs per k
#pragma unroll
    for (int mi = 0; mi < 2; ++mi) {
        int pxx = px0 + wrow * 64 + mi * 32 + ci;
        int bb = pxx / HW_, hh = pxx - bb * HW_;
        ushort* zb = zq + ((size_t)bb * K_ + (k0 + wcol * 64 + 4 * g)) * HW_ + hh;
#pragma unroll
        for (int ni = 0; ni < 2; ++ni)
#pragma unroll
            for (int q = 0; q < 4; ++q)
#pragma unroll
                for (int j = 0; j < 4; ++j) {
                    float s0 = fmaxf((acc[mi][ni][4 * q + j] - ms[mi]) * QSCALE, -32760.f);
                    short v = (short)(int)s0;
                    zb[(size_t)(ni * 32 + 8 * q + j) * HW_] = (ushort)v;
                }
    }
}

// ---------------- combine 16 slab partials ----------------
__global__ void combine_kernel(const float* __restrict__ m_part, const float* __restrict__ l_part,
                               float* __restrict__ m_fin, float* __restrict__ rl_g) {
    int p = blockIdx.x * 256 + threadIdx.x;
    float m = -3.4e38f;
#pragma unroll
    for (int s = 0; s < NSLAB; ++s) m = fmaxf(m, m_part[(size_t)s * NPIX + p]);
    float l = 0.f;
#pragma unroll
    for (int s = 0; s < NSLAB; ++s)
        l += l_part[(size_t)s * NPIX + p] * exp2f((m_part[(size_t)s * NPIX + p] - m) * LOG2E);
    m_fin[p] = m;
    rl_g[p] = 1.0f / l;
}

// ---------------- finish: decode zq -> codes + bow ----------------
__global__ __launch_bounds__(256) void finish_kernel(
    const ushort* __restrict__ zq, const float* __restrict__ m_part,
    const float* __restrict__ m_fin, const float* __restrict__ rl_g,
    float* __restrict__ codes, float* __restrict__ bow)
{
    __shared__ float corr[HW_], rls[HW_];
    __shared__ float bsum[64][4];
    int t = threadIdx.x;
    int kc = blockIdx.x, b = blockIdx.y;
    int slab = kc >> 1;
    for (int i = t; i < HW_; i += 256) {
        int p = b * HW_ + i;
        corr[i] = (m_part[(size_t)slab * NPIX + p] - m_fin[p]) * LOG2E;
        rls[i] = rl_g[p];
    }
    __syncthreads();
    int wid = t >> 6, lane = t & 63;
    for (int kl = 0; kl < 64; ++kl) {
        int k = kc * 64 + kl;
        size_t base = ((size_t)b * K_ + k) * HW_;
        float ssum = 0.f;
        if (t < 196) {
            uint2 raw = *reinterpret_cast<const uint2*>(&zq[base + t * 4]);
            int q0 = (int)(short)(raw.x & 0xffffu), q1 = (int)(short)(raw.x >> 16);
            int q2 = (int)(short)(raw.y & 0xffffu), q3 = (int)(short)(raw.y >> 16);
            float4 out;
            out.x = exp2f(fmaf((float)q0, QDEC, corr[t * 4 + 0])) * rls[t * 4 + 0];
            out.y = exp2f(fmaf((float)q1, QDEC, corr[t * 4 + 1])) * rls[t * 4 + 1];
            out.z = exp2f(fmaf((float)q2, QDEC, corr[t * 4 + 2])) * rls[t * 4 + 2];
            out.w = exp2f(fmaf((float)q3, QDEC, corr[t * 4 + 3])) * rls[t * 4 + 3];
            *reinterpret_cast<float4*>(&codes[base + t * 4]) = out;
            ssum = out.x + out.y + out.z + out.w;
        }
#pragma unroll
        for (int off = 32; off > 0; off >>= 1) ssum += __shfl_xor(ssum, off);
        if (lane == 0) bsum[kl][wid] = ssum;
    }
    __syncthreads();
    if (t < 64) {
        float s = bsum[t][0] + bsum[t][1] + bsum[t][2] + bsum[t][3];
        bow[(size_t)b * K_ + kc * 64 + t] = s * (1.0f / 784.0f);
    }
}

// ---------------- bow row normalize ----------------
__global__ void bownorm_kernel(float* __restrict__ bow) {
    __shared__ float wred[4];
    __shared__ float denom_s;
    int b = blockIdx.x, t = threadIdx.x;
    float* row = bow + (size_t)b * K_;
    float v[8];
    float s = 0.f;
#pragma unroll
    for (int i = 0; i < 8; ++i) {
        v[i] = row[t + i * 256];
        s += fabsf(v[i]);
    }
#pragma unroll
    for (int off = 32; off > 0; off >>= 1) s += __shfl_xor(s, off);
    int wid = t >> 6, lane = t & 63;
    if (lane == 0) wred[wid] = s;
    __syncthreads();
    if (t == 0) denom_s = fmaxf(wred[0] + wred[1] + wred[2] + wred[3], 1e-12f);
    __syncthreads();
    float denom = denom_s;
#pragma unroll
    for (int i = 0; i < 8; ++i) row[t + i * 256] = v[i] / denom;
}

extern "C" void kernel_launch(void* const* d_in, const int* in_sizes, int n_in,
                              void* d_out, int out_size, void* d_ws, size_t ws_size,
                              hipStream_t stream) {
    const float* feat = (const float*)d_in[0];
    const float* emb  = (const float*)d_in[1];
    const float* mdm  = (const float*)d_in[2];
    float* bow   = (float*)d_out;
    float* codes = bow + (size_t)B_ * K_;

    char* ws = (char*)d_ws;
    size_t off = 0;
    auto alloc = [&](size_t bytes) { char* p = ws + off; off = (off + bytes + 255) & ~(size_t)255; return p; };
    ushort* ehi    = (ushort*)alloc((size_t)K_ * C_ * 2);
    ushort* elo    = (ushort*)alloc((size_t)K_ * C_ * 2);
    float*  e2     = (float*)alloc(K_ * 4);
    float*  m_part = (float*)alloc((size_t)NSLAB * NPIX * 4);
    float*  l_part = (float*)alloc((size_t)NSLAB * NPIX * 4);
    float*  m_fin  = (float*)alloc((size_t)NPIX * 4);
    float*  rl_g   = (float*)alloc((size_t)NPIX * 4);
    ushort* zq     = (ushort*)alloc((size_t)NPIX * K_ * 2);

    // fhi/flo live in the codes output region: dead until finish_kernel (stream-ordered).
    ushort* fhi = (ushort*)codes;
    ushort* flo = fhi + (size_t)NPIX * C_;

    e2_kernel<<<512, 256, 0, stream>>>(emb, e2);
    prep_e_kernel<<<2048, 256, 0, stream>>>(emb, ehi, elo);
    prep_f_kernel<<<392, 256, 0, stream>>>(feat, fhi, flo);
    gemm_kernel<<<3136, 256, 0, stream>>>(fhi, flo, ehi, elo, mdm, e2, zq, m_part, l_part);
    combine_kernel<<<98, 256, 0, stream>>>(m_part, l_part, m_fin, rl_g);
    finish_kernel<<<dim3(32, 32), 256, 0, stream>>>(zq, m_part, m_fin, rl_g, codes, bow);
    bownorm_kernel<<<32, 256, 0, stream>>>(bow);
}

// Round 16
// 243.116 us; speedup vs baseline: 1.2221x; 1.2221x over previous
//
#include <hip/hip_runtime.h>
#include <hip/hip_bf16.h>
#include <math.h>

typedef __attribute__((ext_vector_type(8))) short bf16x8;
typedef __attribute__((ext_vector_type(4))) float f32x4;

#define B_ 32
#define C_ 256
#define KP 768           // packed K' = 3*C
#define K_ 2048
#define HW_ 784
#define NPIX 25088
#define FEAT_BSTRIDE 230400
#define FEAT_CSTRIDE 900
#define INV_DELTA 15.0f
#define LOG2E 1.4426950408889634f
#define QSCALE 409.6f
#define QDEC (LOG2E / QSCALE)

#define NSLAB 16         // 2048 / 128

#define AS1 __attribute__((address_space(1)))
#define AS3 __attribute__((address_space(3)))

__device__ __forceinline__ ushort f2bf(float x) {
    __hip_bfloat16 h = __float2bfloat16(x);
    return *reinterpret_cast<ushort*>(&h);
}
__device__ __forceinline__ float bf2f(ushort u) {
    __hip_bfloat16 h;
    *reinterpret_cast<ushort*>(&h) = u;
    return __bfloat162float(h);
}
__device__ __forceinline__ void gl_lds16(const ushort* g, ushort* l) {
    __builtin_amdgcn_global_load_lds((AS1 const uint*)g, (AS3 uint*)l, 16, 0, 0);
}

// ---------------- e2[k] = sum_c emb[k][c]^2 (fp32 exact) ----------------
__global__ void e2_kernel(const float* __restrict__ emb, float* __restrict__ e2) {
    int t = threadIdx.x;
    int wid = t >> 6, lane = t & 63;
    int k = blockIdx.x * 4 + wid;
    const float* er = emb + (size_t)k * C_;
    float v0 = er[lane], v1 = er[lane + 64], v2 = er[lane + 128], v3 = er[lane + 192];
    float s = v0 * v0 + v1 * v1 + v2 * v2 + v3 * v3;
#pragma unroll
    for (int off = 32; off > 0; off >>= 1) s += __shfl_xor(s, off);
    if (lane == 0) e2[k] = s;
}

// ---------------- pack embedding: eB[k][768] = [eh | eh | el] ----------------
__global__ void prep_e_kernel(const float* __restrict__ emb, ushort* __restrict__ eB) {
    int i = blockIdx.x * 256 + threadIdx.x;   // 0 .. 524287
    int k = i >> 8, c = i & 255;
    float v = emb[i];
    ushort h = f2bf(v);
    float r = v - bf2f(h);
    ushort lo = f2bf(r);
    size_t base = (size_t)k * KP;
    eB[base + c] = h;
    eB[base + 256 + c] = h;
    eB[base + 512 + c] = lo;
}

// ---------------- crop+transpose+pack features: fA[px][768] = [fh | fl | fh] ----------------
__global__ __launch_bounds__(256) void prep_f_kernel(const float* __restrict__ feat,
                                                     ushort* __restrict__ fA) {
    __shared__ float F[256 * 65];
    int t = threadIdx.x;
    int px0 = blockIdx.x * 64;
    {
        int lane = t & 63, cq = t >> 6;
        int px = px0 + lane;
        int b = px / HW_, hw = px % HW_;
        int h = hw / 28, w = hw % 28;
        const float* base = feat + (size_t)b * FEAT_BSTRIDE + (size_t)(h + 1) * 30 + (w + 1);
#pragma unroll
        for (int cc = 0; cc < 64; ++cc) {
            int c = cq * 64 + cc;
            F[c * 65 + lane] = base[(size_t)c * FEAT_CSTRIDE];
        }
    }
    __syncthreads();
    {
        int px_l = t >> 2, cseg = t & 3;
        size_t ob = (size_t)(px0 + px_l) * KP;
        uint uh[32], ul[32];
#pragma unroll
        for (int j = 0; j < 32; ++j) {
            float v0 = F[(cseg * 64 + 2 * j) * 65 + px_l];
            float v1 = F[(cseg * 64 + 2 * j + 1) * 65 + px_l];
            ushort h0 = f2bf(v0), h1 = f2bf(v1);
            float r0 = v0 - bf2f(h0), r1 = v1 - bf2f(h1);
            uh[j] = (uint)h0 | ((uint)h1 << 16);
            ul[j] = (uint)f2bf(r0) | ((uint)f2bf(r1) << 16);
        }
#pragma unroll
        for (int j = 0; j < 8; ++j) {
            uint4 vh = *reinterpret_cast<uint4*>(&uh[j * 4]);
            uint4 vl = *reinterpret_cast<uint4*>(&ul[j * 4]);
            *reinterpret_cast<uint4*>(&fA[ob + cseg * 64 + j * 8]) = vh;        // fh
            *reinterpret_cast<uint4*>(&fA[ob + 256 + cseg * 64 + j * 8]) = vl;  // fl
            *reinterpret_cast<uint4*>(&fA[ob + 512 + cseg * 64 + j * 8]) = vh;  // fh
        }
    }
}

// ---------------- GEMM: D[k][px], K'=768, 8 waves, 3-deep LDS, counted vmcnt ----------------
// M = k (128/block), N = px (128/block), 12 K-tiles of BK=64. Per K-tile: one stage
// (kt+2, into the buffer neither read this kt nor next kt), 12 ds_read_b128, one
// lgkmcnt(0)+sched_barrier, 16 MFMA under setprio, one counted vmcnt(4), one barrier.
// Loads stay 2 K-tiles in flight; no drain until the tail (m218 mechanism).
__global__ __launch_bounds__(512, 1) void gemm_kernel(
    const ushort* __restrict__ fA, const ushort* __restrict__ eB,
    const float* __restrict__ mdm, const float* __restrict__ e2g,
    ushort* __restrict__ zq, float* __restrict__ m_part, float* __restrict__ l_part)
{
    __shared__ __align__(16) ushort Ab[3][8192];   // eB tiles: 3 x 16KB (128 k x 64 c)
    __shared__ __align__(16) ushort Bb[3][8192];   // fA tiles: 3 x 16KB (128 px x 64 c)
    __shared__ float redm[2][128], redl[2][128];

    int t = threadIdx.x;
    int lane = t & 63, wid = t >> 6;          // 8 waves
    int wrow = wid >> 2, wcol = wid & 3;      // 2 (k) x 4 (px)
    int lg = lane >> 4, li = lane & 15;

    int bid = blockIdx.x;                     // 0..3135
    int xcd = bid & 7, local = bid >> 3;      // HW round-robins bid%8 over XCDs
    int slab = (xcd << 1) | (local & 1);      // 2 slabs per XCD -> eB L2-resident
    int ntile = local >> 1;                   // 0..195
    int k0 = slab * 128;
    int px0 = ntile * 128;

    auto stage = [&](int buf, int kt) {
        int c0 = kt * 64;
#pragma unroll
        for (int i = 0; i < 2; ++i) {
            int u = t + i * 512;              // 16B unit 0..1023
            int r = u >> 3, q = u & 7;
            int ul = q ^ (r & 7);             // involution (pre-swizzled source, rule 21)
            size_t sa = (size_t)(k0 + r) * KP + c0 + ul * 8;
            size_t sb = (size_t)(px0 + r) * KP + c0 + ul * 8;
            gl_lds16(eB + sa, &Ab[buf][u * 8]);
            gl_lds16(fA + sb, &Bb[buf][u * 8]);
        }
    };

    f32x4 acc[4][2];
#pragma unroll
    for (int mf = 0; mf < 4; ++mf)
#pragma unroll
        for (int nf = 0; nf < 2; ++nf)
            acc[mf][nf] = (f32x4)(0.0f);

    stage(0, 0);
    stage(1, 1);
    asm volatile("s_waitcnt vmcnt(4)" ::: "memory");   // kt0 landed; kt1 in flight
    __builtin_amdgcn_s_barrier();

    for (int kt = 0; kt < 12; ++kt) {
        int buf = kt % 3;
        if (kt + 2 < 12) stage((kt + 2) % 3, kt + 2);  // safe: 3-deep rotation
        // fragment reads (swizzled)
        bf16x8 afr[4][2], bfr[2][2];
#pragma unroll
        for (int mf = 0; mf < 4; ++mf) {
            int r = wrow * 64 + mf * 16 + li;
#pragma unroll
            for (int kk = 0; kk < 2; ++kk) {
                int p = (kk * 4 + lg) ^ (r & 7);
                afr[mf][kk] = *reinterpret_cast<const bf16x8*>(&Ab[buf][r * 64 + p * 8]);
            }
        }
#pragma unroll
        for (int nf = 0; nf < 2; ++nf) {
            int r = wcol * 32 + nf * 16 + li;
#pragma unroll
            for (int kk = 0; kk < 2; ++kk) {
                int p = (kk * 4 + lg) ^ (r & 7);
                bfr[nf][kk] = *reinterpret_cast<const bf16x8*>(&Bb[buf][r * 64 + p * 8]);
            }
        }
        asm volatile("s_waitcnt lgkmcnt(0)" ::: "memory");
        __builtin_amdgcn_sched_barrier(0);             // rule 18: pin MFMAs below the wait
        __builtin_amdgcn_s_setprio(1);
#pragma unroll
        for (int kk = 0; kk < 2; ++kk)
#pragma unroll
            for (int mf = 0; mf < 4; ++mf)
#pragma unroll
                for (int nf = 0; nf < 2; ++nf)
                    acc[mf][nf] = __builtin_amdgcn_mfma_f32_16x16x32_bf16(
                        afr[mf][kk], bfr[nf][kk], acc[mf][nf], 0, 0, 0);
        __builtin_amdgcn_s_setprio(0);
        if (kt < 10) asm volatile("s_waitcnt vmcnt(4)" ::: "memory");  // kt+1 landed, kt+2 in flight
        else         asm volatile("s_waitcnt vmcnt(0)" ::: "memory");  // tail drain
        __builtin_amdgcn_s_barrier();
    }

    // ---------------- epilogue: lane-local k ----------------
    // lane holds z for k = k0 + wrow*64 + mf*16 + lg*4 + reg, px = px0 + wcol*32 + nf*16 + li
    const float alpha = INV_DELTA / mdm[0];
    float4 e2v[4];
#pragma unroll
    for (int mf = 0; mf < 4; ++mf)
        e2v[mf] = *reinterpret_cast<const float4*>(e2g + k0 + wrow * 64 + mf * 16 + lg * 4);
#pragma unroll
    for (int mf = 0; mf < 4; ++mf)
#pragma unroll
        for (int nf = 0; nf < 2; ++nf) {
            acc[mf][nf][0] = alpha * (2.f * acc[mf][nf][0] - e2v[mf].x);
            acc[mf][nf][1] = alpha * (2.f * acc[mf][nf][1] - e2v[mf].y);
            acc[mf][nf][2] = alpha * (2.f * acc[mf][nf][2] - e2v[mf].z);
            acc[mf][nf][3] = alpha * (2.f * acc[mf][nf][3] - e2v[mf].w);
        }

    // per-px max over this wave's 64 k
    float mx[2];
#pragma unroll
    for (int nf = 0; nf < 2; ++nf) {
        float m = acc[0][nf][0];
#pragma unroll
        for (int mf = 0; mf < 4; ++mf)
#pragma unroll
            for (int rg = 0; rg < 4; ++rg) m = fmaxf(m, acc[mf][nf][rg]);
        m = fmaxf(m, __shfl_xor(m, 16));
        m = fmaxf(m, __shfl_xor(m, 32));
        mx[nf] = m;
    }
    if (lane < 16) {
        redm[wrow][wcol * 32 + li] = mx[0];
        redm[wrow][wcol * 32 + 16 + li] = mx[1];
    }
    __syncthreads();
    float msf[2];
#pragma unroll
    for (int nf = 0; nf < 2; ++nf) {
        int pxl = wcol * 32 + nf * 16 + li;
        msf[nf] = fmaxf(redm[0][pxl], redm[1][pxl]);
    }
    // per-px sum of exp over this wave's 64 k
    float sl[2];
#pragma unroll
    for (int nf = 0; nf < 2; ++nf) {
        float s = 0.f;
#pragma unroll
        for (int mf = 0; mf < 4; ++mf)
#pragma unroll
            for (int rg = 0; rg < 4; ++rg)
                s += exp2f((acc[mf][nf][rg] - msf[nf]) * LOG2E);
        s += __shfl_xor(s, 16);
        s += __shfl_xor(s, 32);
        sl[nf] = s;
    }
    if (lane < 16) {
        redl[wrow][wcol * 32 + li] = sl[0];
        redl[wrow][wcol * 32 + 16 + li] = sl[1];
    }
    __syncthreads();
    if (t < 128) {
        m_part[(size_t)slab * NPIX + px0 + t] = fmaxf(redm[0][t], redm[1][t]);
        l_part[(size_t)slab * NPIX + px0 + t] = redl[0][t] + redl[1][t];
    }

    // quantized z store: q = (z - m_slab)*QSCALE int16; 16-px (32B) runs per instruction
#pragma unroll
    for (int mf = 0; mf < 4; ++mf)
#pragma unroll
        for (int rg = 0; rg < 4; ++rg) {
            int k = k0 + wrow * 64 + mf * 16 + lg * 4 + rg;
#pragma unroll
            for (int nf = 0; nf < 2; ++nf) {
                int pxg = px0 + wcol * 32 + nf * 16 + li;
                int bb = pxg / HW_, hh = pxg - bb * HW_;
                float s0 = fmaxf((acc[mf][nf][rg] - msf[nf]) * QSCALE, -32760.f);
                zq[((size_t)bb * K_ + k) * HW_ + hh] = (ushort)(short)(int)s0;
            }
        }
}

// ---------------- combine 16 slab partials ----------------
__global__ void combine_kernel(const float* __restrict__ m_part, const float* __restrict__ l_part,
                               float* __restrict__ m_fin, float* __restrict__ rl_g) {
    int p = blockIdx.x * 256 + threadIdx.x;
    float m = -3.4e38f;
#pragma unroll
    for (int s = 0; s < NSLAB; ++s) m = fmaxf(m, m_part[(size_t)s * NPIX + p]);
    float l = 0.f;
#pragma unroll
    for (int s = 0; s < NSLAB; ++s)
        l += l_part[(size_t)s * NPIX + p] * exp2f((m_part[(size_t)s * NPIX + p] - m) * LOG2E);
    m_fin[p] = m;
    rl_g[p] = 1.0f / l;
}

// ---------------- finish: decode zq -> codes + bow ----------------
__global__ __launch_bounds__(256) void finish_kernel(
    const ushort* __restrict__ zq, const float* __restrict__ m_part,
    const float* __restrict__ m_fin, const float* __restrict__ rl_g,
    float* __restrict__ codes, float* __restrict__ bow)
{
    __shared__ float corr[HW_], rls[HW_];
    __shared__ float bsum[64][4];
    int t = threadIdx.x;
    int kc = blockIdx.x, b = blockIdx.y;
    int slab = kc >> 1;                       // 64-k chunk -> 128-k slab
    for (int i = t; i < HW_; i += 256) {
        int p = b * HW_ + i;
        corr[i] = (m_part[(size_t)slab * NPIX + p] - m_fin[p]) * LOG2E;
        rls[i] = rl_g[p];
    }
    __syncthreads();
    int wid = t >> 6, lane = t & 63;
    for (int kl = 0; kl < 64; ++kl) {
        int k = kc * 64 + kl;
        size_t base = ((size_t)b * K_ + k) * HW_;
        float ssum = 0.f;
        if (t < 196) {
            uint2 raw = *reinterpret_cast<const uint2*>(&zq[base + t * 4]);
            int q0 = (int)(short)(raw.x & 0xffffu), q1 = (int)(short)(raw.x >> 16);
            int q2 = (int)(short)(raw.y & 0xffffu), q3 = (int)(short)(raw.y >> 16);
            float4 out;
            out.x = exp2f(fmaf((float)q0, QDEC, corr[t * 4 + 0])) * rls[t * 4 + 0];
            out.y = exp2f(fmaf((float)q1, QDEC, corr[t * 4 + 1])) * rls[t * 4 + 1];
            out.z = exp2f(fmaf((float)q2, QDEC, corr[t * 4 + 2])) * rls[t * 4 + 2];
            out.w = exp2f(fmaf((float)q3, QDEC, corr[t * 4 + 3])) * rls[t * 4 + 3];
            *reinterpret_cast<float4*>(&codes[base + t * 4]) = out;
            ssum = out.x + out.y + out.z + out.w;
        }
#pragma unroll
        for (int off = 32; off > 0; off >>= 1) ssum += __shfl_xor(ssum, off);
        if (lane == 0) bsum[kl][wid] = ssum;
    }
    __syncthreads();
    if (t < 64) {
        float s = bsum[t][0] + bsum[t][1] + bsum[t][2] + bsum[t][3];
        bow[(size_t)b * K_ + kc * 64 + t] = s * (1.0f / 784.0f);
    }
}

// ---------------- bow row normalize ----------------
__global__ void bownorm_kernel(float* __restrict__ bow) {
    __shared__ float wred[4];
    __shared__ float denom_s;
    int b = blockIdx.x, t = threadIdx.x;
    float* row = bow + (size_t)b * K_;
    float v[8];
    float s = 0.f;
#pragma unroll
    for (int i = 0; i < 8; ++i) {
        v[i] = row[t + i * 256];
        s += fabsf(v[i]);
    }
#pragma unroll
    for (int off = 32; off > 0; off >>= 1) s += __shfl_xor(s, off);
    int wid = t >> 6, lane = t & 63;
    if (lane == 0) wred[wid] = s;
    __syncthreads();
    if (t == 0) denom_s = fmaxf(wred[0] + wred[1] + wred[2] + wred[3], 1e-12f);
    __syncthreads();
    float denom = denom_s;
#pragma unroll
    for (int i = 0; i < 8; ++i) row[t + i * 256] = v[i] / denom;
}

extern "C" void kernel_launch(void* const* d_in, const int* in_sizes, int n_in,
                              void* d_out, int out_size, void* d_ws, size_t ws_size,
                              hipStream_t stream) {
    const float* feat = (const float*)d_in[0];
    const float* emb  = (const float*)d_in[1];
    const float* mdm  = (const float*)d_in[2];
    float* bow   = (float*)d_out;
    float* codes = bow + (size_t)B_ * K_;

    char* ws = (char*)d_ws;
    size_t off = 0;
    auto alloc = [&](size_t bytes) { char* p = ws + off; off = (off + bytes + 255) & ~(size_t)255; return p; };
    ushort* eB     = (ushort*)alloc((size_t)K_ * KP * 2);          // 3.1 MB packed
    float*  e2     = (float*)alloc(K_ * 4);
    float*  m_part = (float*)alloc((size_t)NSLAB * NPIX * 4);
    float*  l_part = (float*)alloc((size_t)NSLAB * NPIX * 4);
    float*  m_fin  = (float*)alloc((size_t)NPIX * 4);
    float*  rl_g   = (float*)alloc((size_t)NPIX * 4);
    ushort* zq     = (ushort*)alloc((size_t)NPIX * K_ * 2);

    // fA (36.8 MB) lives in the codes output region: dead until finish_kernel.
    ushort* fA = (ushort*)codes;

    e2_kernel<<<512, 256, 0, stream>>>(emb, e2);
    prep_e_kernel<<<2048, 256, 0, stream>>>(emb, eB);
    prep_f_kernel<<<392, 256, 0, stream>>>(feat, fA);
    gemm_kernel<<<3136, 512, 0, stream>>>(fA, eB, mdm, e2, zq, m_part, l_part);
    combine_kernel<<<98, 256, 0, stream>>>(m_part, l_part, m_fin, rl_g);
    finish_kernel<<<dim3(32, 32), 256, 0, stream>>>(zq, m_part, m_fin, rl_g, codes, bow);
    bownorm_kernel<<<32, 256, 0, stream>>>(bow);
}